// Round 5
// baseline (4653.429 us; speedup 1.0000x reference)
//
#include <hip/hip_runtime.h>
#include <hip/hip_bf16.h>

#define BATCH 64
#define IN_SIZE 4096
#define IN_DIM 128
#define HEADS 2
#define OUT_SIZE 128
#define NPAIR (BATCH*HEADS)
#define NBLK (NPAIR*2)
#define INV_EPS 10.0f
#define MAX_ITER 50
#define A_MARG (1.0f/32.0f)

typedef unsigned int u32;
typedef __attribute__((ext_vector_type(8))) short bf16x8;
typedef __attribute__((ext_vector_type(4))) float f32x4;

__device__ __forceinline__ float bflo(u32 kk){ return __uint_as_float(kk<<16); }
__device__ __forceinline__ float bfhi(u32 kk){ return __uint_as_float(kk & 0xffff0000u); }
__device__ __forceinline__ unsigned short f2bf(float f){
    __hip_bfloat16 h = __float2bfloat16(f);
    return *(unsigned short*)&h;
}

template<int CTRL>
__device__ __forceinline__ float dpp_add(float x) {
    int yi = __builtin_amdgcn_update_dpp(0, __float_as_int(x), CTRL, 0xf, 0xf, false);
    return x + __int_as_float(yi);
}

// ---------------------------------------------------------------------------
// Kernel 1: kgen (MFMA).  Kb[p][i][o] = bf16(exp(10 * x[n,i,:].w[m,o,:]))
// (unchanged from round 3/4)
// ---------------------------------------------------------------------------
__global__ __launch_bounds__(256) void kgen(const float* __restrict__ x,
                                            const float* __restrict__ w,
                                            __hip_bfloat16* __restrict__ Kb)
{
    const int pair = blockIdx.y;
    const int n = pair >> 1, m = pair & 1;
    const int r0 = blockIdx.x * 128;
    const int tid = threadIdx.x;
    const int wv  = tid >> 6;
    const int l   = tid & 63;

    __shared__ char xs[128*256];
    __shared__ char ws[128*256];

    {
        const float* xb = x + ((size_t)n*IN_SIZE + r0)*IN_DIM;
        for (int t = tid; t < 4096; t += 256) {
            int row = t >> 5, c4 = t & 31;
            float4 v4 = *(const float4*)&xb[(size_t)row*IN_DIM + c4*4];
            u32 p0 = (u32)f2bf(v4.x) | ((u32)f2bf(v4.y) << 16);
            u32 p1 = (u32)f2bf(v4.z) | ((u32)f2bf(v4.w) << 16);
            int byte = (row*256 + c4*8) ^ ((row & 7) << 4);
            *(u32*)(xs + byte)     = p0;
            *(u32*)(xs + byte + 4) = p1;
        }
    }
    {
        const float* wb = w + (size_t)m*OUT_SIZE*IN_DIM;
        for (int t = tid; t < 4096; t += 256) {
            int row = t >> 5, c4 = t & 31;
            float4 v4 = *(const float4*)&wb[(size_t)row*IN_DIM + c4*4];
            u32 p0 = (u32)f2bf(v4.x) | ((u32)f2bf(v4.y) << 16);
            u32 p1 = (u32)f2bf(v4.z) | ((u32)f2bf(v4.w) << 16);
            int byte = (row*256 + c4*8) ^ ((row & 7) << 4);
            *(u32*)(ws + byte)     = p0;
            *(u32*)(ws + byte + 4) = p1;
        }
    }
    __syncthreads();

    f32x4 acc[2][8];
    #pragma unroll
    for (int ai=0;ai<2;++ai)
        #pragma unroll
        for (int bj=0;bj<8;++bj) acc[ai][bj] = (f32x4){0.f,0.f,0.f,0.f};

    const int lr = l & 15;
    const int lk = (l >> 4) * 16;

    #pragma unroll
    for (int kk = 0; kk < 4; ++kk) {
        bf16x8 a[2];
        #pragma unroll
        for (int ai=0;ai<2;++ai) {
            int row = wv*32 + ai*16 + lr;
            int byte = (row*256 + kk*64 + lk) ^ ((row & 7) << 4);
            a[ai] = *(const bf16x8*)(xs + byte);
        }
        #pragma unroll
        for (int bj=0;bj<8;++bj) {
            int row = bj*16 + lr;
            int byte = (row*256 + kk*64 + lk) ^ ((row & 7) << 4);
            bf16x8 b = *(const bf16x8*)(ws + byte);
            acc[0][bj] = __builtin_amdgcn_mfma_f32_16x16x32_bf16(a[0], b, acc[0][bj], 0, 0, 0);
            acc[1][bj] = __builtin_amdgcn_mfma_f32_16x16x32_bf16(a[1], b, acc[1][bj], 0, 0, 0);
        }
    }

    __hip_bfloat16* out = Kb + (size_t)pair*IN_SIZE*OUT_SIZE + (size_t)r0*OUT_SIZE;
    #pragma unroll
    for (int ai=0;ai<2;++ai) {
        #pragma unroll
        for (int bj=0;bj<8;++bj) {
            #pragma unroll
            for (int j=0;j<4;++j) {
                int i = wv*32 + ai*16 + (l>>4)*4 + j;
                int o = bj*16 + lr;
                float e = __expf(INV_EPS * acc[ai][bj][j]);
                out[(size_t)i*OUT_SIZE + o] = __float2bfloat16(e);
            }
        }
    }
}

// ---------------------------------------------------------------------------
// Kernel 2: sinkhorn. 256 blocks x 1024 thr, 1 block/CU, half-pair per block.
// K residency per wave's 128 rows (32 quads): 16 quads in VGPRs (64 u32/thr),
// 8 quads in LDS (self-slot, no conflicts), 8 quads streamed (L2-resident,
// depth-4 prefetch rotating across the iteration seam).
// Exchange: round-4 fence-free sign-sentinel slots (unchanged).
// ---------------------------------------------------------------------------
#define PROC_QUAD(cc, qidx)                                                   \
    {                                                                         \
        float k0=bflo((cc).x), k1=bfhi((cc).x), k2=bflo((cc).y), k3=bfhi((cc).y); \
        float k4=bflo((cc).z), k5=bfhi((cc).z), k6=bflo((cc).w), k7=bfhi((cc).w); \
        float p = k0*v[0];                                                    \
        p = fmaf(k1,v[1],p); p = fmaf(k2,v[2],p); p = fmaf(k3,v[3],p);        \
        p = fmaf(k4,v[4],p); p = fmaf(k5,v[5],p); p = fmaf(k6,v[6],p);        \
        p = fmaf(k7,v[7],p);                                                  \
        p = dpp_add<0xB1>(p);                                                 \
        p = dpp_add<0x4E>(p);                                                 \
        p = dpp_add<0x141>(p);                                                \
        p = dpp_add<0x140>(p);                                                \
        float ui = A_MARG * __builtin_amdgcn_rcpf(p);                         \
        acc[0]=fmaf(ui,k0,acc[0]); acc[1]=fmaf(ui,k1,acc[1]);                 \
        acc[2]=fmaf(ui,k2,acc[2]); acc[3]=fmaf(ui,k3,acc[3]);                 \
        acc[4]=fmaf(ui,k4,acc[4]); acc[5]=fmaf(ui,k5,acc[5]);                 \
        acc[6]=fmaf(ui,k6,acc[6]); acc[7]=fmaf(ui,k7,acc[7]);                 \
        if (last && s == 0) uo[uob + (qidx)*4 + grp] = ui;                    \
    }

__global__ __launch_bounds__(1024, 4) void sinkhorn(const __hip_bfloat16* __restrict__ Kb,
                                                    float* __restrict__ uo,
                                                    float* __restrict__ vo,
                                                    int* __restrict__ slots)
{
    const int bid  = blockIdx.x;
    const int pair = bid >> 1, half = bid & 1;
    const int tid  = threadIdx.x;
    const int wave = tid >> 6;      // 16 waves, 128 rows each
    const int lane = tid & 63;
    const int grp  = lane >> 4;     // row within quad
    const int s    = lane & 15;     // column slice 8s..8s+7

    __shared__ int4  klds[16*8*64]; // 131072 B: [wave][q][lane] self-slots
    __shared__ float red[16][128];  //   8192 B
    __shared__ float vnew[128];     //    512 B

    const int4* gp = (const int4*)(Kb)
                   + ((size_t)pair*4096 + half*2048 + wave*128)*16
                   + grp*16 + s;
    const size_t uob = (size_t)pair*IN_SIZE + half*2048 + wave*128;

    // ---- one-time load: 16 quads -> registers, 8 quads -> LDS ----
    int4 kq0  = gp[ 0*64], kq1  = gp[ 1*64], kq2  = gp[ 2*64], kq3  = gp[ 3*64];
    int4 kq4  = gp[ 4*64], kq5  = gp[ 5*64], kq6  = gp[ 6*64], kq7  = gp[ 7*64];
    int4 kq8  = gp[ 8*64], kq9  = gp[ 9*64], kq10 = gp[10*64], kq11 = gp[11*64];
    int4 kq12 = gp[12*64], kq13 = gp[13*64], kq14 = gp[14*64], kq15 = gp[15*64];
    #pragma unroll
    for (int q = 0; q < 8; ++q)
        klds[(wave*8 + q)*64 + lane] = gp[(16+q)*64];

    const int4* sp = gp + 24*64;    // streamed quads 24..31

    float v[8];
    #pragma unroll
    for (int j=0;j<8;++j) v[j] = 1.f;

    // rotating depth-4 prefetch of streamed quads (addresses iteration-invariant)
    int4 c0 = sp[0*64], c1 = sp[1*64], c2 = sp[2*64], c3 = sp[3*64];

    for (int it = 0; it < MAX_ITER; ++it) {
        const bool last = (it == MAX_ITER-1);
        float acc[8];
        #pragma unroll
        for (int j=0;j<8;++j) acc[j] = 0.f;

        // ---- register-resident quads (pure VALU, covers prefetch latency) ----
        PROC_QUAD(kq0,  0)  PROC_QUAD(kq1,  1)  PROC_QUAD(kq2,  2)  PROC_QUAD(kq3,  3)
        PROC_QUAD(kq4,  4)  PROC_QUAD(kq5,  5)  PROC_QUAD(kq6,  6)  PROC_QUAD(kq7,  7)
        PROC_QUAD(kq8,  8)  PROC_QUAD(kq9,  9)  PROC_QUAD(kq10,10)  PROC_QUAD(kq11,11)
        PROC_QUAD(kq12,12)  PROC_QUAD(kq13,13)  PROC_QUAD(kq14,14)  PROC_QUAD(kq15,15)

        // ---- LDS-resident quads ----
        #pragma unroll
        for (int q = 0; q < 8; ++q) {
            int4 cc = klds[(wave*8 + q)*64 + lane];
            PROC_QUAD(cc, 16+q)
        }

        // ---- streamed quads with rotation (wraps into next iteration) ----
        #pragma unroll
        for (int g = 0; g < 8; ++g) {
            int4 nx = sp[(size_t)((g+4)&7)*64];
            PROC_QUAD(c0, 24+g)
            c0 = c1; c1 = c2; c2 = c3; c3 = nx;
        }

        // ---- column-sum reduce + cross-block exchange ----
        #pragma unroll
        for (int j=0;j<8;++j) {
            acc[j] += __shfl_xor(acc[j], 16, 64);
            acc[j] += __shfl_xor(acc[j], 32, 64);
        }
        if (lane < 16) {
            *(float4*)&red[wave][8*s]   = make_float4(acc[0],acc[1],acc[2],acc[3]);
            *(float4*)&red[wave][8*s+4] = make_float4(acc[4],acc[5],acc[6],acc[7]);
        }
        __syncthreads();
        if (tid < 128) {
            float own = 0.f;
            #pragma unroll
            for (int w_ = 0; w_ < 16; ++w_) own += red[w_][tid];
            int* myslot = slots + ((size_t)it*NBLK + bid)*128;
            int* otslot = slots + ((size_t)it*NBLK + (bid^1))*128;
            __hip_atomic_store(&myslot[tid], __float_as_int(-own),
                               __ATOMIC_RELAXED, __HIP_MEMORY_SCOPE_AGENT);
            int wrd;
            do {
                wrd = __hip_atomic_load(&otslot[tid], __ATOMIC_RELAXED,
                                        __HIP_MEMORY_SCOPE_AGENT);
            } while (wrd >= 0);
            float other = -__int_as_float(wrd);
            float vv = __builtin_amdgcn_rcpf(own + other);
            vnew[tid] = vv;
            if (last && half == 0) vo[(size_t)pair*OUT_SIZE + tid] = vv;
        }
        __syncthreads();
        float4 va = *(const float4*)&vnew[8*s];
        float4 vb = *(const float4*)&vnew[8*s+4];
        v[0]=va.x; v[1]=va.y; v[2]=va.z; v[3]=va.w;
        v[4]=vb.x; v[5]=vb.y; v[6]=vb.z; v[7]=vb.w;
    }
}

// ---------------------------------------------------------------------------
// Kernel 3: outgemm (MFMA).  (unchanged from round 4)
// ---------------------------------------------------------------------------
__global__ __launch_bounds__(256) void outgemm(const __hip_bfloat16* __restrict__ Kb,
                                               const float* __restrict__ uo,
                                               const float* __restrict__ vo,
                                               const float* __restrict__ x,
                                               float* __restrict__ out)
{
    const int dh = blockIdx.x;
    const int pair = blockIdx.y;
    const int n = pair >> 1, m = pair & 1;
    const int tid = threadIdx.x;
    const int wv  = tid >> 6;
    const int l   = tid & 63;

    __shared__ u32  ka[64][66];
    __shared__ float ua[64];
    __shared__ float xa[64][68];
    __shared__ char At[128*128];
    __shared__ char Bt[64*128];

    f32x4 acc[2][4];
    #pragma unroll
    for (int ai=0;ai<2;++ai)
        #pragma unroll
        for (int bj=0;bj<4;++bj) acc[ai][bj] = (f32x4){0.f,0.f,0.f,0.f};

    const int lr = l & 15;
    const int lk = (l >> 4) * 16;

    for (int chunk = 0; chunk < 64; ++chunk) {
        const int i0 = chunk * 64;
        {
            const u32* ksrc = (const u32*)(Kb + ((size_t)pair*IN_SIZE + i0)*OUT_SIZE);
            for (int t = tid; t < 4096; t += 256) ka[t>>6][t&63] = ksrc[t];
            if (tid < 64) ua[tid] = uo[(size_t)pair*IN_SIZE + i0 + tid];
            const float* xsrc = x + ((size_t)n*IN_SIZE + i0)*IN_DIM + dh*64;
            for (int t = tid; t < 1024; t += 256) {
                int i = t >> 4, c4 = t & 15;
                *(float4*)&xa[i][c4*4] = *(const float4*)&xsrc[(size_t)i*IN_DIM + c4*4];
            }
        }
        __syncthreads();
        {
            int o = tid >> 1, seg = tid & 1;
            unsigned short us[32];
            #pragma unroll
            for (int k=0;k<32;++k) {
                int i = seg*32 + k;
                u32 kk = ka[i][o>>1];
                float f = (o&1) ? bfhi(kk) : bflo(kk);
                us[k] = f2bf(f * ua[i]);
            }
            #pragma unroll
            for (int q=0;q<4;++q) {
                int4 wbuf;
                u32* wp = (u32*)&wbuf;
                #pragma unroll
                for (int e=0;e<4;++e)
                    wp[e] = (u32)us[q*8 + 2*e] | ((u32)us[q*8 + 2*e + 1] << 16);
                int byte = (o*128 + seg*64 + q*16) ^ ((o & 7) << 4);
                *(int4*)(At + byte) = wbuf;
            }
        }
        {
            int d = tid >> 2, s2 = tid & 3;
            unsigned short us[16];
            #pragma unroll
            for (int k=0;k<16;++k) us[k] = f2bf(xa[s2*16 + k][d]);
            #pragma unroll
            for (int q=0;q<2;++q) {
                int4 wbuf;
                u32* wp = (u32*)&wbuf;
                #pragma unroll
                for (int e=0;e<4;++e)
                    wp[e] = (u32)us[q*8 + 2*e] | ((u32)us[q*8 + 2*e + 1] << 16);
                int byte = (d*128 + s2*32 + q*16) ^ ((d & 7) << 4);
                *(int4*)(Bt + byte) = wbuf;
            }
        }
        __syncthreads();
        #pragma unroll
        for (int kk = 0; kk < 2; ++kk) {
            bf16x8 a[2];
            #pragma unroll
            for (int ai=0;ai<2;++ai) {
                int row = wv*32 + ai*16 + lr;
                int byte = (row*128 + kk*64 + lk) ^ ((row & 7) << 4);
                a[ai] = *(const bf16x8*)(At + byte);
            }
            #pragma unroll
            for (int bj=0;bj<4;++bj) {
                int row = bj*16 + lr;
                int byte = (row*128 + kk*64 + lk) ^ ((row & 7) << 4);
                bf16x8 b = *(const bf16x8*)(Bt + byte);
                acc[0][bj] = __builtin_amdgcn_mfma_f32_16x16x32_bf16(a[0], b, acc[0][bj], 0, 0, 0);
                acc[1][bj] = __builtin_amdgcn_mfma_f32_16x16x32_bf16(a[1], b, acc[1][bj], 0, 0, 0);
            }
        }
        __syncthreads();
    }

    #pragma unroll
    for (int ai=0;ai<2;++ai) {
        #pragma unroll
        for (int bj=0;bj<4;++bj) {
            #pragma unroll
            for (int j=0;j<4;++j) {
                int o = wv*32 + ai*16 + (l>>4)*4 + j;
                int d = dh*64 + bj*16 + lr;
                float vv = vo[(size_t)pair*OUT_SIZE + o];
                out[(((size_t)n*OUT_SIZE + o)*HEADS + m)*IN_DIM + d] = acc[ai][bj][j] * vv;
            }
        }
    }
}

// ---------------------------------------------------------------------------
extern "C" void kernel_launch(void* const* d_in, const int* in_sizes, int n_in,
                              void* d_out, int out_size, void* d_ws, size_t ws_size,
                              hipStream_t stream)
{
    const float* x = (const float*)d_in[0];
    const float* w = (const float*)d_in[1];
    float* out = (float*)d_out;

    char* ws = (char*)d_ws;
    __hip_bfloat16* Kb = (__hip_bfloat16*)ws;                 // 134,217,728 B
    float* uo  = (float*)(ws + 134217728);                    //   2,097,152 B
    float* vo  = (float*)(ws + 134217728 + 2097152);          //      65,536 B
    int* slots = (int*)(ws + 134217728 + 2097152 + 65536);    //   6,553,600 B

    // slots MUST be zeroed (0xAA poison has sign bit set -> false sentinel)
    hipMemsetAsync(slots, 0, (size_t)MAX_ITER*NBLK*128*sizeof(int), stream);

    kgen    <<<dim3(IN_SIZE/128, NPAIR), 256,  0, stream>>>(x, w, Kb);
    sinkhorn<<<dim3(NBLK),               1024, 0, stream>>>(Kb, uo, vo, slots);
    outgemm <<<dim3(2, NPAIR),           256,  0, stream>>>(Kb, uo, vo, x, out);
}

// Round 7
// 4518.090 us; speedup vs baseline: 1.0300x; 1.0300x over previous
//
#include <hip/hip_runtime.h>
#include <hip/hip_bf16.h>

#define BATCH 64
#define IN_SIZE 4096
#define IN_DIM 128
#define HEADS 2
#define OUT_SIZE 128
#define NPAIR (BATCH*HEADS)
#define NBLK (NPAIR*2)
#define INV_EPS 10.0f
#define MAX_ITER 50
#define A_MARG (1.0f/32.0f)

typedef unsigned int u32;
typedef __attribute__((ext_vector_type(8))) short bf16x8;
typedef __attribute__((ext_vector_type(4))) float f32x4;

__device__ __forceinline__ float bflo(u32 kk){ return __uint_as_float(kk<<16); }
__device__ __forceinline__ float bfhi(u32 kk){ return __uint_as_float(kk & 0xffff0000u); }
__device__ __forceinline__ unsigned short f2bf(float f){
    __hip_bfloat16 h = __float2bfloat16(f);
    return *(unsigned short*)&h;
}

template<int CTRL>
__device__ __forceinline__ float dpp_add(float x) {
    int yi = __builtin_amdgcn_update_dpp(0, __float_as_int(x), CTRL, 0xf, 0xf, false);
    return x + __int_as_float(yi);
}

// ---------------------------------------------------------------------------
// Kernel 1: kgen (MFMA).  Kb[p][i][o] = bf16(exp(10 * x[n,i,:].w[m,o,:]))
// (unchanged)
// ---------------------------------------------------------------------------
__global__ __launch_bounds__(256) void kgen(const float* __restrict__ x,
                                            const float* __restrict__ w,
                                            __hip_bfloat16* __restrict__ Kb)
{
    const int pair = blockIdx.y;
    const int n = pair >> 1, m = pair & 1;
    const int r0 = blockIdx.x * 128;
    const int tid = threadIdx.x;
    const int wv  = tid >> 6;
    const int l   = tid & 63;

    __shared__ char xs[128*256];
    __shared__ char ws[128*256];

    {
        const float* xb = x + ((size_t)n*IN_SIZE + r0)*IN_DIM;
        for (int t = tid; t < 4096; t += 256) {
            int row = t >> 5, c4 = t & 31;
            float4 v4 = *(const float4*)&xb[(size_t)row*IN_DIM + c4*4];
            u32 p0 = (u32)f2bf(v4.x) | ((u32)f2bf(v4.y) << 16);
            u32 p1 = (u32)f2bf(v4.z) | ((u32)f2bf(v4.w) << 16);
            int byte = (row*256 + c4*8) ^ ((row & 7) << 4);
            *(u32*)(xs + byte)     = p0;
            *(u32*)(xs + byte + 4) = p1;
        }
    }
    {
        const float* wb = w + (size_t)m*OUT_SIZE*IN_DIM;
        for (int t = tid; t < 4096; t += 256) {
            int row = t >> 5, c4 = t & 31;
            float4 v4 = *(const float4*)&wb[(size_t)row*IN_DIM + c4*4];
            u32 p0 = (u32)f2bf(v4.x) | ((u32)f2bf(v4.y) << 16);
            u32 p1 = (u32)f2bf(v4.z) | ((u32)f2bf(v4.w) << 16);
            int byte = (row*256 + c4*8) ^ ((row & 7) << 4);
            *(u32*)(ws + byte)     = p0;
            *(u32*)(ws + byte + 4) = p1;
        }
    }
    __syncthreads();

    f32x4 acc[2][8];
    #pragma unroll
    for (int ai=0;ai<2;++ai)
        #pragma unroll
        for (int bj=0;bj<8;++bj) acc[ai][bj] = (f32x4){0.f,0.f,0.f,0.f};

    const int lr = l & 15;
    const int lk = (l >> 4) * 16;

    #pragma unroll
    for (int kk = 0; kk < 4; ++kk) {
        bf16x8 a[2];
        #pragma unroll
        for (int ai=0;ai<2;++ai) {
            int row = wv*32 + ai*16 + lr;
            int byte = (row*256 + kk*64 + lk) ^ ((row & 7) << 4);
            a[ai] = *(const bf16x8*)(xs + byte);
        }
        #pragma unroll
        for (int bj=0;bj<8;++bj) {
            int row = bj*16 + lr;
            int byte = (row*256 + kk*64 + lk) ^ ((row & 7) << 4);
            bf16x8 b = *(const bf16x8*)(ws + byte);
            acc[0][bj] = __builtin_amdgcn_mfma_f32_16x16x32_bf16(a[0], b, acc[0][bj], 0, 0, 0);
            acc[1][bj] = __builtin_amdgcn_mfma_f32_16x16x32_bf16(a[1], b, acc[1][bj], 0, 0, 0);
        }
    }

    __hip_bfloat16* out = Kb + (size_t)pair*IN_SIZE*OUT_SIZE + (size_t)r0*OUT_SIZE;
    #pragma unroll
    for (int ai=0;ai<2;++ai) {
        #pragma unroll
        for (int bj=0;bj<8;++bj) {
            #pragma unroll
            for (int j=0;j<4;++j) {
                int i = wv*32 + ai*16 + (l>>4)*4 + j;
                int o = bj*16 + lr;
                float e = __expf(INV_EPS * acc[ai][bj][j]);
                out[(size_t)i*OUT_SIZE + o] = __float2bfloat16(e);
            }
        }
    }
}

// ---------------------------------------------------------------------------
// Kernel 2: sinkhorn. 256 blocks x 1024 thr, 1 block/CU, half-pair per block.
// K residency per wave's 128 rows (32 quads): 14 quads in VGPRs (56 u32/thr),
// 9 quads in LDS (self-slot), 9 quads streamed (depth-4 ring prefetch
// wrapping the iteration seam). launch_bounds(1024,1) -> VGPR cap 128
// (round-5's (1024,4) was interpreted as blocks/CU -> 64-reg cap -> spill).
// Exchange: fence-free sign-sentinel slots (round 4, proven).
// ---------------------------------------------------------------------------
#define PROC_QUAD(cc, qidx)                                                   \
    {                                                                         \
        float k0=bflo((cc).x), k1=bfhi((cc).x), k2=bflo((cc).y), k3=bfhi((cc).y); \
        float k4=bflo((cc).z), k5=bfhi((cc).z), k6=bflo((cc).w), k7=bfhi((cc).w); \
        float p = k0*v[0];                                                    \
        p = fmaf(k1,v[1],p); p = fmaf(k2,v[2],p); p = fmaf(k3,v[3],p);        \
        p = fmaf(k4,v[4],p); p = fmaf(k5,v[5],p); p = fmaf(k6,v[6],p);        \
        p = fmaf(k7,v[7],p);                                                  \
        p = dpp_add<0xB1>(p);                                                 \
        p = dpp_add<0x4E>(p);                                                 \
        p = dpp_add<0x141>(p);                                                \
        p = dpp_add<0x140>(p);                                                \
        float ui = A_MARG * __builtin_amdgcn_rcpf(p);                         \
        acc[0]=fmaf(ui,k0,acc[0]); acc[1]=fmaf(ui,k1,acc[1]);                 \
        acc[2]=fmaf(ui,k2,acc[2]); acc[3]=fmaf(ui,k3,acc[3]);                 \
        acc[4]=fmaf(ui,k4,acc[4]); acc[5]=fmaf(ui,k5,acc[5]);                 \
        acc[6]=fmaf(ui,k6,acc[6]); acc[7]=fmaf(ui,k7,acc[7]);                 \
        if (last && s == 0) uo[uob + (qidx)*4 + grp] = ui;                    \
    }

#define NREG 14
#define NLDS 9
#define NSTR 9

__global__ __launch_bounds__(1024, 1) void sinkhorn(const __hip_bfloat16* __restrict__ Kb,
                                                    float* __restrict__ uo,
                                                    float* __restrict__ vo,
                                                    int* __restrict__ slots)
{
    const int bid  = blockIdx.x;
    const int pair = bid >> 1, half = bid & 1;
    const int tid  = threadIdx.x;
    const int wave = tid >> 6;      // 16 waves, 128 rows each
    const int lane = tid & 63;
    const int grp  = lane >> 4;     // row within quad
    const int s    = lane & 15;     // column slice 8s..8s+7

    __shared__ int4  klds[16*NLDS*64];  // 147456 B self-slots
    __shared__ float red[16][128];      //   8192 B
    __shared__ float vnew[128];         //    512 B

    const int4* gp = (const int4*)(Kb)
                   + ((size_t)pair*4096 + half*2048 + wave*128)*16
                   + grp*16 + s;
    const size_t uob = (size_t)pair*IN_SIZE + half*2048 + wave*128;

    // ---- one-time load: 14 quads -> registers, 9 quads -> LDS ----
    int4 kq0  = gp[ 0*64], kq1  = gp[ 1*64], kq2  = gp[ 2*64], kq3  = gp[ 3*64];
    int4 kq4  = gp[ 4*64], kq5  = gp[ 5*64], kq6  = gp[ 6*64], kq7  = gp[ 7*64];
    int4 kq8  = gp[ 8*64], kq9  = gp[ 9*64], kq10 = gp[10*64], kq11 = gp[11*64];
    int4 kq12 = gp[12*64], kq13 = gp[13*64];
    #pragma unroll
    for (int q = 0; q < NLDS; ++q)
        klds[(wave*NLDS + q)*64 + lane] = gp[(NREG+q)*64];

    const int4* sp = gp + (NREG+NLDS)*64;   // streamed quads 23..31

    float v[8];
    #pragma unroll
    for (int j=0;j<8;++j) v[j] = 1.f;

    // depth-4 rotating prefetch of the 9 streamed quads (addresses
    // iteration-invariant; ring wraps across the iteration seam)
    int4 c0 = sp[0*64], c1 = sp[1*64], c2 = sp[2*64], c3 = sp[3*64];

    for (int it = 0; it < MAX_ITER; ++it) {
        const bool last = (it == MAX_ITER-1);
        float acc[8];
        #pragma unroll
        for (int j=0;j<8;++j) acc[j] = 0.f;

        // ---- register-resident quads ----
        PROC_QUAD(kq0,  0)  PROC_QUAD(kq1,  1)  PROC_QUAD(kq2,  2)  PROC_QUAD(kq3,  3)
        PROC_QUAD(kq4,  4)  PROC_QUAD(kq5,  5)  PROC_QUAD(kq6,  6)  PROC_QUAD(kq7,  7)
        PROC_QUAD(kq8,  8)  PROC_QUAD(kq9,  9)  PROC_QUAD(kq10,10)  PROC_QUAD(kq11,11)
        PROC_QUAD(kq12,12)  PROC_QUAD(kq13,13)

        // ---- LDS-resident quads (self-slot reads, no barrier needed) ----
        #pragma unroll
        for (int q = 0; q < NLDS; ++q) {
            int4 cc = klds[(wave*NLDS + q)*64 + lane];
            PROC_QUAD(cc, NREG+q)
        }

        // ---- streamed quads, depth-4 ring wrapping into next iteration ----
        #pragma unroll
        for (int g = 0; g < NSTR; ++g) {
            const int nxi = (g+4 < NSTR) ? (g+4) : (g+4-NSTR);
            int4 nx = sp[(size_t)nxi*64];
            PROC_QUAD(c0, NREG+NLDS+g)
            c0 = c1; c1 = c2; c2 = c3; c3 = nx;
        }

        // ---- column-sum reduce + cross-block exchange ----
        #pragma unroll
        for (int j=0;j<8;++j) {
            acc[j] += __shfl_xor(acc[j], 16, 64);
            acc[j] += __shfl_xor(acc[j], 32, 64);
        }
        if (lane < 16) {
            *(float4*)&red[wave][8*s]   = make_float4(acc[0],acc[1],acc[2],acc[3]);
            *(float4*)&red[wave][8*s+4] = make_float4(acc[4],acc[5],acc[6],acc[7]);
        }
        __syncthreads();
        if (tid < 128) {
            float own = 0.f;
            #pragma unroll
            for (int w_ = 0; w_ < 16; ++w_) own += red[w_][tid];
            int* myslot = slots + ((size_t)it*NBLK + bid)*128;
            int* otslot = slots + ((size_t)it*NBLK + (bid^1))*128;
            __hip_atomic_store(&myslot[tid], __float_as_int(-own),
                               __ATOMIC_RELAXED, __HIP_MEMORY_SCOPE_AGENT);
            int wrd;
            do {
                wrd = __hip_atomic_load(&otslot[tid], __ATOMIC_RELAXED,
                                        __HIP_MEMORY_SCOPE_AGENT);
            } while (wrd >= 0);
            float other = -__int_as_float(wrd);
            float vv = __builtin_amdgcn_rcpf(own + other);
            vnew[tid] = vv;
            if (last && half == 0) vo[(size_t)pair*OUT_SIZE + tid] = vv;
        }
        __syncthreads();
        float4 va = *(const float4*)&vnew[8*s];
        float4 vb = *(const float4*)&vnew[8*s+4];
        v[0]=va.x; v[1]=va.y; v[2]=va.z; v[3]=va.w;
        v[4]=vb.x; v[5]=vb.y; v[6]=vb.z; v[7]=vb.w;
    }
}

// ---------------------------------------------------------------------------
// Kernel 3: outgemm (MFMA).  (unchanged)
// ---------------------------------------------------------------------------
__global__ __launch_bounds__(256) void outgemm(const __hip_bfloat16* __restrict__ Kb,
                                               const float* __restrict__ uo,
                                               const float* __restrict__ vo,
                                               const float* __restrict__ x,
                                               float* __restrict__ out)
{
    const int dh = blockIdx.x;
    const int pair = blockIdx.y;
    const int n = pair >> 1, m = pair & 1;
    const int tid = threadIdx.x;
    const int wv  = tid >> 6;
    const int l   = tid & 63;

    __shared__ u32  ka[64][66];
    __shared__ float ua[64];
    __shared__ float xa[64][68];
    __shared__ char At[128*128];
    __shared__ char Bt[64*128];

    f32x4 acc[2][4];
    #pragma unroll
    for (int ai=0;ai<2;++ai)
        #pragma unroll
        for (int bj=0;bj<4;++bj) acc[ai][bj] = (f32x4){0.f,0.f,0.f,0.f};

    const int lr = l & 15;
    const int lk = (l >> 4) * 16;

    for (int chunk = 0; chunk < 64; ++chunk) {
        const int i0 = chunk * 64;
        {
            const u32* ksrc = (const u32*)(Kb + ((size_t)pair*IN_SIZE + i0)*OUT_SIZE);
            for (int t = tid; t < 4096; t += 256) ka[t>>6][t&63] = ksrc[t];
            if (tid < 64) ua[tid] = uo[(size_t)pair*IN_SIZE + i0 + tid];
            const float* xsrc = x + ((size_t)n*IN_SIZE + i0)*IN_DIM + dh*64;
            for (int t = tid; t < 1024; t += 256) {
                int i = t >> 4, c4 = t & 15;
                *(float4*)&xa[i][c4*4] = *(const float4*)&xsrc[(size_t)i*IN_DIM + c4*4];
            }
        }
        __syncthreads();
        {
            int o = tid >> 1, seg = tid & 1;
            unsigned short us[32];
            #pragma unroll
            for (int k=0;k<32;++k) {
                int i = seg*32 + k;
                u32 kk = ka[i][o>>1];
                float f = (o&1) ? bfhi(kk) : bflo(kk);
                us[k] = f2bf(f * ua[i]);
            }
            #pragma unroll
            for (int q=0;q<4;++q) {
                int4 wbuf;
                u32* wp = (u32*)&wbuf;
                #pragma unroll
                for (int e=0;e<4;++e)
                    wp[e] = (u32)us[q*8 + 2*e] | ((u32)us[q*8 + 2*e + 1] << 16);
                int byte = (o*128 + seg*64 + q*16) ^ ((o & 7) << 4);
                *(int4*)(At + byte) = wbuf;
            }
        }
        {
            int d = tid >> 2, s2 = tid & 3;
            unsigned short us[16];
            #pragma unroll
            for (int k=0;k<16;++k) us[k] = f2bf(xa[s2*16 + k][d]);
            #pragma unroll
            for (int q=0;q<2;++q) {
                int4 wbuf;
                u32* wp = (u32*)&wbuf;
                #pragma unroll
                for (int e=0;e<4;++e)
                    wp[e] = (u32)us[q*8 + 2*e] | ((u32)us[q*8 + 2*e + 1] << 16);
                int byte = (d*128 + s2*32 + q*16) ^ ((d & 7) << 4);
                *(int4*)(Bt + byte) = wbuf;
            }
        }
        __syncthreads();
        #pragma unroll
        for (int kk = 0; kk < 2; ++kk) {
            bf16x8 a[2];
            #pragma unroll
            for (int ai=0;ai<2;++ai) {
                int row = wv*32 + ai*16 + lr;
                int byte = (row*128 + kk*64 + lk) ^ ((row & 7) << 4);
                a[ai] = *(const bf16x8*)(At + byte);
            }
            #pragma unroll
            for (int bj=0;bj<4;++bj) {
                int row = bj*16 + lr;
                int byte = (row*128 + kk*64 + lk) ^ ((row & 7) << 4);
                bf16x8 b = *(const bf16x8*)(Bt + byte);
                acc[0][bj] = __builtin_amdgcn_mfma_f32_16x16x32_bf16(a[0], b, acc[0][bj], 0, 0, 0);
                acc[1][bj] = __builtin_amdgcn_mfma_f32_16x16x32_bf16(a[1], b, acc[1][bj], 0, 0, 0);
            }
        }
        __syncthreads();
    }

    #pragma unroll
    for (int ai=0;ai<2;++ai) {
        #pragma unroll
        for (int bj=0;bj<4;++bj) {
            #pragma unroll
            for (int j=0;j<4;++j) {
                int o = wv*32 + ai*16 + (l>>4)*4 + j;
                int d = dh*64 + bj*16 + lr;
                float vv = vo[(size_t)pair*OUT_SIZE + o];
                out[(((size_t)n*OUT_SIZE + o)*HEADS + m)*IN_DIM + d] = acc[ai][bj][j] * vv;
            }
        }
    }
}

// ---------------------------------------------------------------------------
extern "C" void kernel_launch(void* const* d_in, const int* in_sizes, int n_in,
                              void* d_out, int out_size, void* d_ws, size_t ws_size,
                              hipStream_t stream)
{
    const float* x = (const float*)d_in[0];
    const float* w = (const float*)d_in[1];
    float* out = (float*)d_out;

    char* ws = (char*)d_ws;
    __hip_bfloat16* Kb = (__hip_bfloat16*)ws;                 // 134,217,728 B
    float* uo  = (float*)(ws + 134217728);                    //   2,097,152 B
    float* vo  = (float*)(ws + 134217728 + 2097152);          //      65,536 B
    int* slots = (int*)(ws + 134217728 + 2097152 + 65536);    //   6,553,600 B

    // slots MUST be zeroed (0xAA poison has sign bit set -> false sentinel)
    hipMemsetAsync(slots, 0, (size_t)MAX_ITER*NBLK*128*sizeof(int), stream);

    kgen    <<<dim3(IN_SIZE/128, NPAIR), 256,  0, stream>>>(x, w, Kb);
    sinkhorn<<<dim3(NBLK),               1024, 0, stream>>>(Kb, uo, vo, slots);
    outgemm <<<dim3(2, NPAIR),           256,  0, stream>>>(Kb, uo, vo, x, out);
}